// Round 1
// baseline (138.410 us; speedup 1.0000x reference)
//
#include <hip/hip_runtime.h>

#define NPTS   262144
#define CIN    16
#define COUT   32
#define NTAPS  27
#define BLK    256

__global__ __launch_bounds__(BLK) void sct_fp32_kernel(
    const float* __restrict__ feat,   // [N, CIN]
    const float* __restrict__ Wg,     // [27, CIN, COUT]
    const float* __restrict__ bias,   // [COUT]
    const int*   __restrict__ nbr,    // [N, 27]
    float*       __restrict__ out)    // [N, COUT]
{
    __shared__ float wl[NTAPS * CIN * COUT];   // 55296 B
    for (int i = threadIdx.x; i < NTAPS * CIN * COUT; i += BLK)
        wl[i] = Wg[i];
    __syncthreads();

    const int j = blockIdx.x * BLK + threadIdx.x;

    float acc[COUT];
#pragma unroll
    for (int c = 0; c < COUT; ++c) acc[c] = bias[c];

    const long jbase = (long)j * NTAPS;

    for (int t = 0; t < NTAPS; ++t) {        // rolled: keep code size sane
        const int id = nbr[jbase + t];
        const bool v = (id >= 0);
        const int safe = v ? id : 0;
        const float4* fp = (const float4*)(feat + (long)safe * CIN);
        float4 f0 = fp[0];
        float4 f1 = fp[1];
        float4 f2 = fp[2];
        float4 f3 = fp[3];
        if (!v) {
            f0 = make_float4(0.f, 0.f, 0.f, 0.f);
            f1 = make_float4(0.f, 0.f, 0.f, 0.f);
            f2 = make_float4(0.f, 0.f, 0.f, 0.f);
            f3 = make_float4(0.f, 0.f, 0.f, 0.f);
        }
        float fr[CIN];
        fr[0]  = f0.x; fr[1]  = f0.y; fr[2]  = f0.z; fr[3]  = f0.w;
        fr[4]  = f1.x; fr[5]  = f1.y; fr[6]  = f1.z; fr[7]  = f1.w;
        fr[8]  = f2.x; fr[9]  = f2.y; fr[10] = f2.z; fr[11] = f2.w;
        fr[12] = f3.x; fr[13] = f3.y; fr[14] = f3.z; fr[15] = f3.w;

        const float4* wrow = (const float4*)&wl[t * CIN * COUT];
#pragma unroll
        for (int cin = 0; cin < CIN; ++cin) {
            const float fv = fr[cin];
#pragma unroll
            for (int q = 0; q < COUT / 4; ++q) {
                const float4 w4 = wrow[cin * (COUT / 4) + q];  // wave-uniform broadcast
                acc[q * 4 + 0] += w4.x * fv;
                acc[q * 4 + 1] += w4.y * fv;
                acc[q * 4 + 2] += w4.z * fv;
                acc[q * 4 + 3] += w4.w * fv;
            }
        }
    }

    float4* op = (float4*)(out + (long)j * COUT);
#pragma unroll
    for (int q = 0; q < COUT / 4; ++q)
        op[q] = make_float4(acc[q * 4 + 0], acc[q * 4 + 1],
                            acc[q * 4 + 2], acc[q * 4 + 3]);
}

extern "C" void kernel_launch(void* const* d_in, const int* in_sizes, int n_in,
                              void* d_out, int out_size, void* d_ws, size_t ws_size,
                              hipStream_t stream) {
    const float* feat = (const float*)d_in[0];
    const float* Wg   = (const float*)d_in[1];
    const float* bias = (const float*)d_in[2];
    const int*   nbr  = (const int*)d_in[3];
    float*       out  = (float*)d_out;

    const int n = in_sizes[0] / CIN;   // 262144 points
    sct_fp32_kernel<<<n / BLK, BLK, 0, stream>>>(feat, Wg, bias, nbr, out);
}

// Round 2
// 63.663 us; speedup vs baseline: 2.1741x; 2.1741x over previous
//
#include <hip/hip_runtime.h>
#include <hip/hip_bf16.h>

#define NPTS  262144
#define CIN   16
#define COUT  32
#define NTAPS 27
#define BLK   256

typedef __attribute__((ext_vector_type(8)))  short short8v;   // 8 bf16 (4 VGPRs)
typedef __attribute__((ext_vector_type(16))) float f32x16;    // MFMA accumulator

// Prep: convert fp32 features -> bf16 in workspace (one float4 per thread).
__global__ __launch_bounds__(BLK) void cvt_feat_kernel(
    const float* __restrict__ feat, __hip_bfloat16* __restrict__ fb)
{
    const int i = blockIdx.x * BLK + threadIdx.x;
    const float4 x = ((const float4*)feat)[i];
    __hip_bfloat162* o = (__hip_bfloat162*)fb;
    o[2 * i]     = __float22bfloat162_rn(float2{x.x, x.y});
    o[2 * i + 1] = __float22bfloat162_rn(float2{x.z, x.w});
}

// Main: per wave, 32 points x 32 cout via 27x v_mfma_f32_32x32x16_bf16.
// Logical K of each MFMA = 16 cin of one tap; A and B fragments both packed
// with cin = (lane>>5)*8 + e, so the HW k-permutation cancels (symmetric A/B).
template<bool USE_WS>
__global__ __launch_bounds__(BLK, 5) void sct_mfma_kernel(
    const float* __restrict__ feat,            // [N,16] fp32
    const __hip_bfloat16* __restrict__ featb,  // [N,16] bf16 (ws), if USE_WS
    const float* __restrict__ Wg,              // [27,16,32] fp32
    const float* __restrict__ bias,            // [32]
    const int*   __restrict__ nbr,             // [N,27]
    float*       __restrict__ out)             // [N,32]
{
    // B fragments pre-packed in LDS: bpack[tap][lane][e] = W[tap][(lane>>5)*8+e][lane&31]
    __shared__ short bpack[NTAPS * 512];       // 27648 B -> 5 blocks/CU

    const int tid = threadIdx.x;
    for (int i = tid; i < NTAPS * 512; i += BLK) {
        const int tap  = i >> 9;
        const int r    = i & 511;
        const int ln   = r >> 3;
        const int e    = r & 7;
        const int cin  = ((ln >> 5) << 3) + e;
        const int cout = ln & 31;
        const float w = Wg[(tap * CIN + cin) * COUT + cout];
        const __hip_bfloat16 h = __float2bfloat16(w);
        bpack[i] = *(const short*)&h;
    }
    __syncthreads();

    const int lane = tid & 63;
    const int wv   = tid >> 6;                       // wave in block: 0..3
    const int p0   = blockIdx.x * 128 + wv * 32;     // this wave's 32 points
    const int prow = lane & 31;                      // A-row (point) / B-col (cout)
    const int g    = lane >> 5;                      // k-group
    const int p    = p0 + prow;

    f32x16 acc;
    {
        const float b = bias[prow];                  // all 16 regs share cout=prow
        #pragma unroll
        for (int r2 = 0; r2 < 16; ++r2) acc[r2] = b;
    }

    const int nbase = p * NTAPS;

    for (int tap = 0; tap < NTAPS; ++tap) {
        const int id   = nbr[nbase + tap];
        const int safe = id < 0 ? 0 : id;
        short8v af;
        if (USE_WS) {
            af = *(const short8v*)(featb + (long)safe * CIN + g * 8);
        } else {
            const float4* fp = (const float4*)(feat + (long)safe * CIN + g * 8);
            const float4 x = fp[0];
            const float4 y = fp[1];
            union { short8v v; __hip_bfloat162 h[4]; } u;
            u.h[0] = __float22bfloat162_rn(float2{x.x, x.y});
            u.h[1] = __float22bfloat162_rn(float2{x.z, x.w});
            u.h[2] = __float22bfloat162_rn(float2{y.x, y.y});
            u.h[3] = __float22bfloat162_rn(float2{y.z, y.w});
            af = u.v;
        }
        const short8v zero = {};
        if (id < 0) af = zero;                       // invalid tap -> 0 contribution
        const short8v bf = *(const short8v*)&bpack[(tap << 9) + (lane << 3)];
        acc = __builtin_amdgcn_mfma_f32_32x32x16_bf16(af, bf, acc, 0, 0, 0);
    }

    // D: col = lane&31 (cout), row = (reg&3) + 8*(reg>>2) + 4*(lane>>5) (point)
    #pragma unroll
    for (int r2 = 0; r2 < 16; ++r2) {
        const int row = (r2 & 3) + 8 * (r2 >> 2) + 4 * g;
        out[(long)(p0 + row) * COUT + prow] = acc[r2];
    }
}

extern "C" void kernel_launch(void* const* d_in, const int* in_sizes, int n_in,
                              void* d_out, int out_size, void* d_ws, size_t ws_size,
                              hipStream_t stream) {
    const float* feat = (const float*)d_in[0];
    const float* Wg   = (const float*)d_in[1];
    const float* bias = (const float*)d_in[2];
    const int*   nbr  = (const int*)d_in[3];
    float*       out  = (float*)d_out;

    const size_t need = (size_t)NPTS * CIN * sizeof(__hip_bfloat16);  // 8 MB
    if (ws_size >= need) {
        __hip_bfloat16* fb = (__hip_bfloat16*)d_ws;
        cvt_feat_kernel<<<NPTS * CIN / 4 / BLK, BLK, 0, stream>>>(feat, fb);
        sct_mfma_kernel<true><<<NPTS / 128, BLK, 0, stream>>>(feat, fb, Wg, bias, nbr, out);
    } else {
        sct_mfma_kernel<false><<<NPTS / 128, BLK, 0, stream>>>(feat, nullptr, Wg, bias, nbr, out);
    }
}

// Round 3
// 44.223 us; speedup vs baseline: 3.1298x; 1.4396x over previous
//
#include <hip/hip_runtime.h>
#include <hip/hip_bf16.h>

#define NPTS  262144
#define CIN   16
#define COUT  32
#define NTAPS 27
#define BLK   512

typedef __attribute__((ext_vector_type(8)))  short short8v;   // 8 bf16 (4 VGPRs)
typedef __attribute__((ext_vector_type(16))) float f32x16;    // MFMA accumulator

// Prep: convert fp32 features -> bf16 in workspace (one float4 per thread).
__global__ __launch_bounds__(256) void cvt_feat_kernel(
    const float* __restrict__ feat, __hip_bfloat16* __restrict__ fb)
{
    const int i = blockIdx.x * 256 + threadIdx.x;
    const float4 x = ((const float4*)feat)[i];
    __hip_bfloat162* o = (__hip_bfloat162*)fb;
    o[2 * i]     = __float22bfloat162_rn(float2{x.x, x.y});
    o[2 * i + 1] = __float22bfloat162_rn(float2{x.z, x.w});
}

// Per wave: 32 points x 32 cout via 27x v_mfma_f32_32x32x16_bf16.
// A and B fragments both packed with cin = (lane>>5)*8 + e, so the HW
// k-permutation cancels (symmetric A/B packing; verified round 2).
// Gathers are exec-masked (only ~12.5% of taps valid) and software-pipelined
// in groups of 4 with depth-2 double buffering (8 gathers in flight).
template<bool USE_WS>
__global__ __launch_bounds__(BLK, 6) void sct_mfma_kernel(
    const float* __restrict__ feat,            // [N,16] fp32
    const __hip_bfloat16* __restrict__ featb,  // [N,16] bf16 (ws)
    const float* __restrict__ Wg,              // [27,16,32] fp32
    const float* __restrict__ bias,            // [32]
    const int*   __restrict__ nbr,             // [N,27]
    float*       __restrict__ out)             // [N,32]
{
    __shared__ short bpack[NTAPS * 512];       // 27648 B, one copy per 8 waves

    const int tid = threadIdx.x;
    for (int i = tid; i < NTAPS * 512; i += BLK) {
        const int tap  = i >> 9;
        const int r    = i & 511;
        const int ln   = r >> 3;
        const int e    = r & 7;
        const int cin  = ((ln >> 5) << 3) + e;
        const int cout = ln & 31;
        const __hip_bfloat16 h = __float2bfloat16(Wg[(tap * CIN + cin) * COUT + cout]);
        bpack[i] = *(const short*)&h;
    }
    __syncthreads();

    const int lane = tid & 63;
    const int wv   = tid >> 6;                        // 0..7
    const int p0   = blockIdx.x * 256 + wv * 32;      // this wave's 32 points
    const int prow = lane & 31;                       // A-row (point) / B-col (cout)
    const int g    = lane >> 5;                       // k-group
    const long nbase = (long)(p0 + prow) * NTAPS;

    f32x16 acc;
    {
        const float b = bias[prow];
        #pragma unroll
        for (int r2 = 0; r2 < 16; ++r2) acc[r2] = b;
    }

    auto gather1 = [&](int id, short8v& dst) {
        short8v a = {};
        if (id >= 0) {                                 // exec-masked: no traffic for invalid
            if (USE_WS) {
                a = *(const short8v*)(featb + (long)id * CIN + g * 8);
            } else {
                const float4* fp = (const float4*)(feat + (long)id * CIN + g * 8);
                const float4 x = fp[0];
                const float4 y = fp[1];
                union { short8v v; __hip_bfloat162 h[4]; } u;
                u.h[0] = __float22bfloat162_rn(float2{x.x, x.y});
                u.h[1] = __float22bfloat162_rn(float2{x.z, x.w});
                u.h[2] = __float22bfloat162_rn(float2{y.x, y.y});
                u.h[3] = __float22bfloat162_rn(float2{y.z, y.w});
                a = u.v;
            }
        }
        dst = a;
    };

    int4    nid[2];
    short8v af[2][4];

    // prologue: group 0 (taps 0..3)
    nid[0] = *(const int4*)(nbr + nbase);
    gather1(nid[0].x, af[0][0]);
    gather1(nid[0].y, af[0][1]);
    gather1(nid[0].z, af[0][2]);
    gather1(nid[0].w, af[0][3]);

    #pragma unroll
    for (int grp = 0; grp < 7; ++grp) {               // fully unrolled -> static idx
        const int cur = grp & 1, nxt = cur ^ 1;
        if (grp < 6) {                                 // prefetch next group
            if (grp == 5) {                            // taps 24..26 (avoid OOB int4)
                const int2 t = *(const int2*)(nbr + nbase + 24);
                nid[nxt] = make_int4(t.x, t.y, nbr[nbase + 26], -1);
            } else {
                nid[nxt] = *(const int4*)(nbr + nbase + 4 * (grp + 1));
            }
            gather1(nid[nxt].x, af[nxt][0]);
            gather1(nid[nxt].y, af[nxt][1]);
            gather1(nid[nxt].z, af[nxt][2]);
            gather1(nid[nxt].w, af[nxt][3]);
        }
        const int ntaps_cur = (grp == 6) ? 3 : 4;
        #pragma unroll
        for (int k = 0; k < 4; ++k) {
            if (k < ntaps_cur) {
                const int tap = 4 * grp + k;
                const short8v bf = *(const short8v*)&bpack[(tap << 9) + (lane << 3)];
                acc = __builtin_amdgcn_mfma_f32_32x32x16_bf16(af[cur][k], bf, acc, 0, 0, 0);
            }
        }
    }

    // D: col = lane&31 (cout), row = (reg&3) + 8*(reg>>2) + 4*(lane>>5) (point)
    #pragma unroll
    for (int r2 = 0; r2 < 16; ++r2) {
        const int row = (r2 & 3) + 8 * (r2 >> 2) + 4 * g;
        out[(long)(p0 + row) * COUT + prow] = acc[r2];
    }
}

extern "C" void kernel_launch(void* const* d_in, const int* in_sizes, int n_in,
                              void* d_out, int out_size, void* d_ws, size_t ws_size,
                              hipStream_t stream) {
    const float* feat = (const float*)d_in[0];
    const float* Wg   = (const float*)d_in[1];
    const float* bias = (const float*)d_in[2];
    const int*   nbr  = (const int*)d_in[3];
    float*       out  = (float*)d_out;

    const size_t need = (size_t)NPTS * CIN * sizeof(__hip_bfloat16);  // 8 MB
    if (ws_size >= need) {
        __hip_bfloat16* fb = (__hip_bfloat16*)d_ws;
        cvt_feat_kernel<<<NPTS * CIN / 4 / 256, 256, 0, stream>>>(feat, fb);
        sct_mfma_kernel<true><<<NPTS / 256, BLK, 0, stream>>>(feat, fb, Wg, bias, nbr, out);
    } else {
        sct_mfma_kernel<false><<<NPTS / 256, BLK, 0, stream>>>(feat, nullptr, Wg, bias, nbr, out);
    }
}

// Round 4
// 43.863 us; speedup vs baseline: 3.1555x; 1.0082x over previous
//
#include <hip/hip_runtime.h>
#include <hip/hip_bf16.h>

#define NPTS  262144
#define CIN   16
#define COUT  32
#define NTAPS 27
#define BLK   512
#define DEPTH 12            // gathers in flight per wave (ring buffers)

typedef __attribute__((ext_vector_type(8)))  short short8v;   // 8 bf16 (4 VGPRs)
typedef __attribute__((ext_vector_type(16))) float f32x16;    // MFMA accumulator

// Prep: convert fp32 features -> bf16 in workspace (one float4 per thread).
__global__ __launch_bounds__(256) void cvt_feat_kernel(
    const float* __restrict__ feat, __hip_bfloat16* __restrict__ fb)
{
    const int i = blockIdx.x * 256 + threadIdx.x;
    const float4 x = ((const float4*)feat)[i];
    __hip_bfloat162* o = (__hip_bfloat162*)fb;
    o[2 * i]     = __float22bfloat162_rn(float2{x.x, x.y});
    o[2 * i + 1] = __float22bfloat162_rn(float2{x.z, x.w});
}

// Per wave: 32 points x 32 cout via 27x v_mfma_f32_32x32x16_bf16.
// Symmetric A/B fragment packing (cin = (lane>>5)*8 + e on both sides) so the
// HW k-permutation cancels — verified rounds 2-3.
// This round: all 27 nbr ids preloaded up front (one latency payment), and a
// 12-deep gather ring so each MFMA's operand was issued ~11 taps (~220 cyc)
// earlier. Steady state per tap: {ds_read bpack, MFMA, issue gather t+12}.
template<bool USE_WS>
__global__ __launch_bounds__(BLK, 3) void sct_mfma_kernel(
    const float* __restrict__ feat,            // [N,16] fp32
    const __hip_bfloat16* __restrict__ featb,  // [N,16] bf16 (ws)
    const float* __restrict__ Wg,              // [27,16,32] fp32
    const float* __restrict__ bias,            // [32]
    const int*   __restrict__ nbr,             // [N,27]
    float*       __restrict__ out)             // [N,32]
{
    __shared__ short bpack[NTAPS * 512];       // 27648 B, one copy per 8 waves

    const int tid = threadIdx.x;
    for (int i = tid; i < NTAPS * 512; i += BLK) {
        const int tap  = i >> 9;
        const int r    = i & 511;
        const int ln   = r >> 3;
        const int e    = r & 7;
        const int cin  = ((ln >> 5) << 3) + e;
        const int cout = ln & 31;
        const __hip_bfloat16 h = __float2bfloat16(Wg[(tap * CIN + cin) * COUT + cout]);
        bpack[i] = *(const short*)&h;
    }
    __syncthreads();

    const int lane = tid & 63;
    const int wv   = tid >> 6;                        // 0..7
    const int p0   = blockIdx.x * 256 + wv * 32;      // this wave's 32 points
    const int prow = lane & 31;                       // A-row (point) / B-col (cout)
    const int g    = lane >> 5;                       // k-group
    const int* nb  = nbr + (long)(p0 + prow) * NTAPS;

    // --- all 27 neighbor ids up front: issue 8 loads back-to-back, one wait ---
    int nid[NTAPS];
    #pragma unroll
    for (int q = 0; q < 6; ++q) {
        const int4 v = *(const int4*)(nb + 4 * q);
        nid[4*q+0] = v.x; nid[4*q+1] = v.y; nid[4*q+2] = v.z; nid[4*q+3] = v.w;
    }
    {
        const int2 v2 = *(const int2*)(nb + 24);
        nid[24] = v2.x; nid[25] = v2.y; nid[26] = nb[26];
    }

    f32x16 acc;
    {
        const float b = bias[prow];
        #pragma unroll
        for (int r2 = 0; r2 < 16; ++r2) acc[r2] = b;
    }

    short8v af[DEPTH];

    auto gather1 = [&](int t, short8v& dst) {
        const int id = nid[t];
        short8v a = {};
        if (id >= 0) {                                 // exec-masked (~12.5% valid)
            if (USE_WS) {
                a = *(const short8v*)(featb + (long)id * CIN + g * 8);
            } else {
                const float4* fp = (const float4*)(feat + (long)id * CIN + g * 8);
                const float4 x = fp[0];
                const float4 y = fp[1];
                union { short8v v; __hip_bfloat162 h[4]; } u;
                u.h[0] = __float22bfloat162_rn(float2{x.x, x.y});
                u.h[1] = __float22bfloat162_rn(float2{x.z, x.w});
                u.h[2] = __float22bfloat162_rn(float2{y.x, y.y});
                u.h[3] = __float22bfloat162_rn(float2{y.z, y.w});
                a = u.v;
            }
        }
        dst = a;
    };

    // prologue: 12 gathers in flight
    #pragma unroll
    for (int t = 0; t < DEPTH; ++t) gather1(t, af[t]);

    // steady state: consume tap t, refill slot with tap t+12
    #pragma unroll
    for (int t = 0; t < NTAPS; ++t) {
        const short8v bf = *(const short8v*)&bpack[(t << 9) + (lane << 3)];
        acc = __builtin_amdgcn_mfma_f32_32x32x16_bf16(af[t % DEPTH], bf, acc, 0, 0, 0);
        if (t + DEPTH < NTAPS) gather1(t + DEPTH, af[(t + DEPTH) % DEPTH]);
    }

    // D: col = lane&31 (cout), row = (reg&3) + 8*(reg>>2) + 4*(lane>>5) (point)
    #pragma unroll
    for (int r2 = 0; r2 < 16; ++r2) {
        const int row = (r2 & 3) + 8 * (r2 >> 2) + 4 * g;
        out[(long)(p0 + row) * COUT + prow] = acc[r2];
    }
}

extern "C" void kernel_launch(void* const* d_in, const int* in_sizes, int n_in,
                              void* d_out, int out_size, void* d_ws, size_t ws_size,
                              hipStream_t stream) {
    const float* feat = (const float*)d_in[0];
    const float* Wg   = (const float*)d_in[1];
    const float* bias = (const float*)d_in[2];
    const int*   nbr  = (const int*)d_in[3];
    float*       out  = (float*)d_out;

    const size_t need = (size_t)NPTS * CIN * sizeof(__hip_bfloat16);  // 8 MB
    if (ws_size >= need) {
        __hip_bfloat16* fb = (__hip_bfloat16*)d_ws;
        cvt_feat_kernel<<<NPTS * CIN / 4 / 256, 256, 0, stream>>>(feat, fb);
        sct_mfma_kernel<true><<<NPTS / 256, BLK, 0, stream>>>(feat, fb, Wg, bias, nbr, out);
    } else {
        sct_mfma_kernel<false><<<NPTS / 256, BLK, 0, stream>>>(feat, nullptr, Wg, bias, nbr, out);
    }
}